// Round 10
// baseline (658.920 us; speedup 1.0000x reference)
//
#include <hip/hip_runtime.h>

// Problem constants
static constexpr int NN   = 50000;
static constexpr int EE   = 800000;
static constexpr int GG   = 256;
static constexpr int NBLK = (NN + 255) / 256;   // 196
static constexpr int PCH  = 16;                 // pooling chunks per graph

typedef float f32x2 __attribute__((ext_vector_type(2)));   // native vec for NT store

// ---------- helpers ----------
__device__ __forceinline__ int lowerb(const int* __restrict__ b, int n, int v) {
    int lo = 0, hi = n;
    while (lo < hi) { int m = (lo + hi) >> 1; if (b[m] < v) lo = m + 1; else hi = m; }
    return lo;
}

// ---------- CSR build (by target node = col) ----------
__global__ void count_k(const int* __restrict__ ei, int* __restrict__ cnt)
{
    int e = blockIdx.x * 256 + threadIdx.x;
    if (e < EE) atomicAdd(&cnt[ei[EE + e]], 1);
}

__global__ __launch_bounds__(256) void bsum_k(const int* __restrict__ cnt, int* __restrict__ bsum)
{
    __shared__ int s[256];
    int b = blockIdx.x, t = threadIdx.x;
    int i = b * 256 + t;
    s[t] = (i < NN) ? cnt[i] : 0;
    __syncthreads();
    #pragma unroll
    for (int off = 128; off > 0; off >>= 1) {
        if (t < off) s[t] += s[t + off];
        __syncthreads();
    }
    if (t == 0) bsum[b] = s[0];
}

__global__ __launch_bounds__(256) void scanb_k(const int* __restrict__ bsum, int* __restrict__ boff)
{
    __shared__ int s[256];
    int t = threadIdx.x;
    int v = (t < NBLK) ? bsum[t] : 0;
    s[t] = v;
    __syncthreads();
    #pragma unroll
    for (int off = 1; off < 256; off <<= 1) {
        int add = (t >= off) ? s[t - off] : 0;
        __syncthreads();
        s[t] += add;
        __syncthreads();
    }
    boff[t] = s[t] - v;   // exclusive
}

__global__ __launch_bounds__(256) void emit_k(const int* __restrict__ cnt,
                                              const int* __restrict__ boff,
                                              int* __restrict__ rowptr,
                                              int* __restrict__ cursor,
                                              float* __restrict__ dinv)
{
    __shared__ int s[256];
    int b = blockIdx.x, t = threadIdx.x;
    int i = b * 256 + t;
    int v = (i < NN) ? cnt[i] : 0;
    s[t] = v;
    __syncthreads();
    #pragma unroll
    for (int off = 1; off < 256; off <<= 1) {
        int add = (t >= off) ? s[t - off] : 0;
        __syncthreads();
        s[t] += add;
        __syncthreads();
    }
    int run = boff[b] + s[t] - v;   // exclusive prefix
    if (i < NN) {
        rowptr[i] = run;
        cursor[i] = run;
        dinv[i]   = rsqrtf((float)(v + 1));   // deg includes self-loop
        if (i == NN - 1) rowptr[NN] = run + v;
    }
}

// fill ushort src records — scattered 2B writes over 1.6 MB span (merges in L2)
__global__ void fill_k(const int* __restrict__ ei, int* __restrict__ cursor,
                       unsigned short* __restrict__ esrc)
{
    int e = blockIdx.x * 256 + threadIdx.x;
    if (e < EE) {
        int r = ei[e];          // source (< 50000 < 65536)
        int c = ei[EE + e];     // target
        int p = atomicAdd(&cursor[c], 1);
        esrc[p] = (unsigned short)r;
    }
}

// ---------- GEMM: out sliced [8][rows][16], PRESCALED by dinv[r] ----------
// in: plain rows (S=0) or sliced (S=1). ts[r] = dinv[r] * (in[r] @ W)
template<int SLICED_IN>
__global__ __launch_bounds__(256) void gemm128s_k(const float* __restrict__ in,
                                                  const float* __restrict__ W,
                                                  const float* __restrict__ dinv,
                                                  float* __restrict__ out,
                                                  int rows)
{
    int r = blockIdx.x * 256 + threadIdx.x;
    if (r >= rows) return;
    int c0 = blockIdx.y * 32;
    float di = dinv[r];

    float acc[32];
    #pragma unroll
    for (int j = 0; j < 32; j++) acc[j] = 0.f;

    for (int k0 = 0; k0 < 128; k0 += 8) {
        const float* bp = SLICED_IN
            ? in + ((size_t)(k0 >> 4) * rows + r) * 16 + (k0 & 8)
            : in + (size_t)r * 128 + k0;
        float4 ra = *(const float4*)(bp);
        float4 rb = *(const float4*)(bp + 4);
        float rr[8] = {ra.x, ra.y, ra.z, ra.w, rb.x, rb.y, rb.z, rb.w};
        #pragma unroll
        for (int kk = 0; kk < 8; kk++) {
            const float* wr = W + (size_t)(k0 + kk) * 128 + c0;   // wave-uniform -> s_load
            #pragma unroll
            for (int j = 0; j < 32; j++) acc[j] = fmaf(rr[kk], wr[j], acc[j]);
        }
    }
    #pragma unroll
    for (int j = 0; j < 32; j++) acc[j] *= di;     // prescale: edge loop needs no norm
    int s0 = c0 >> 4;                       // covers slices s0, s0+1
    float* o0 = out + ((size_t)s0 * rows + r) * 16;
    float* o1 = out + ((size_t)(s0 + 1) * rows + r) * 16;
    #pragma unroll
    for (int j = 0; j < 4; j++) {
        *(float4*)(o0 + j * 4) = make_float4(acc[4*j], acc[4*j+1], acc[4*j+2], acc[4*j+3]);
        *(float4*)(o1 + j * 4) = make_float4(acc[16+4*j], acc[17+4*j], acc[18+4*j], acc[19+4*j]);
    }
}

// ---------- XCD-sliced aggregation v3: node-per-wave, prescaled input ----------
// grid (8, NN/4), block 256 = 4 waves. blockIdx.x = slice -> XCD (id%8).
// Wave = 8 edge-slots x 8 lanes x float2 (512 B/gather-instr). Edge loop is
// index->gather->add only (dinv folded into ts by GEMM). Divergence-free:
// one node per wave. out = di * (ts_i + sum ts_src) + b.
// ROWMAJOR_OUT=1 writes out[i][128] (conv3/recon); else sliced Bs + optional relu.
template<int ROWMAJOR_OUT, int RELU>
__global__ __launch_bounds__(256) void aggs3_k(const float* __restrict__ As,
                                               const int* __restrict__ rowptr,
                                               const unsigned short* __restrict__ esrc,
                                               const float* __restrict__ dinv,
                                               const float* __restrict__ bias,
                                               float* __restrict__ out)
{
    int sl   = blockIdx.x;                 // slice 0..7
    int w    = threadIdx.x >> 6;           // wave 0..3
    int lane = threadIdx.x & 63;
    int slot = lane >> 3;                  // edge slot 0..7
    int l    = lane & 7;                   // float2 feat idx 0..7
    int i    = blockIdx.y * 4 + w;         // NN = 50000 = 12500*4 exact
    const f32x2* Asl = (const f32x2*)(As + (size_t)sl * NN * 16);
    float di = dinv[i];
    int e0 = rowptr[i], e1 = rowptr[i + 1];

    f32x2 acc; acc.x = 0.f; acc.y = 0.f;
    int e = e0 + slot;
    for (; e + 8 < e1; e += 16) {          // unroll x2: 2 indep chains per slot
        int sA = esrc[e];
        int sB = esrc[e + 8];
        f32x2 vA = Asl[(size_t)sA * 8 + l];
        f32x2 vB = Asl[(size_t)sB * 8 + l];
        acc.x += vA.x + vB.x;
        acc.y += vA.y + vB.y;
    }
    if (e < e1) {
        int s = esrc[e];
        f32x2 v = Asl[(size_t)s * 8 + l];
        acc.x += v.x; acc.y += v.y;
    }
    if (slot == 0) {                       // self-loop term: ts_i
        f32x2 v = Asl[(size_t)i * 8 + l];
        acc.x += v.x; acc.y += v.y;
    }
    // reduce across 8 slots (lane bits 3,4,5)
    acc.x += __shfl_xor(acc.x, 8);  acc.y += __shfl_xor(acc.y, 8);
    acc.x += __shfl_xor(acc.x, 16); acc.y += __shfl_xor(acc.y, 16);
    acc.x += __shfl_xor(acc.x, 32); acc.y += __shfl_xor(acc.y, 32);
    if (slot == 0) {
        f32x2 b = ((const f32x2*)bias)[sl * 8 + l];
        f32x2 o;
        o.x = di * acc.x + b.x;
        o.y = di * acc.y + b.y;
        if (RELU) { o.x = fmaxf(o.x, 0.f); o.y = fmaxf(o.y, 0.f); }
        if (ROWMAJOR_OUT)
            __builtin_nontemporal_store(o, (f32x2*)(out + (size_t)i * 128 + sl * 16) + l);
        else
            __builtin_nontemporal_store(o, (f32x2*)(out + ((size_t)sl * NN + i) * 16) + l);
    }
}

// ---------- conv3 prescale: ts3s[sl][j][16] = dinv[j] * zz[batch[j]][sl*16+k] ----------
// linear tid -> coalesced writes; zz (128 KB) + batch L2-resident
__global__ __launch_bounds__(256) void scale_k(const float* __restrict__ zz,
                                               const int* __restrict__ batch,
                                               const float* __restrict__ dinv,
                                               float* __restrict__ ts3s)
{
    int t = blockIdx.x * 256 + threadIdx.x;        // 8*NN*16 total
    int sl  = t >> 4 ;                             // decompose: t = (sl*NN + j)*16 + k
    int k   = t & 15;
    int jj  = (t >> 4) % NN;
    sl = t / (NN * 16);
    ts3s[t] = dinv[jj] * zz[(size_t)batch[jj] * 128 + sl * 16 + k];
}

// ---------- pooling (parallel, sliced input) ----------
__global__ __launch_bounds__(128) void pool2_k(const float* __restrict__ Bs,
                                               const int* __restrict__ batch,
                                               float* __restrict__ pooled)
{
    int g = blockIdx.x;
    int c = blockIdx.y;
    int f = threadIdx.x;                       // 0..127
    int sl = f >> 4, off = f & 15;
    const float* Bsl = Bs + ((size_t)sl * NN) * 16 + off;
    int bs = lowerb(batch, NN, g);
    int be = lowerb(batch, NN, g + 1);
    int len = be - bs;
    int cs = bs + (int)(((long long)len * c) / PCH);
    int ce = bs + (int)(((long long)len * (c + 1)) / PCH);
    float a = 0.f;
    for (int i = cs; i < ce; i++) a += Bsl[(size_t)i * 16];
    if (ce > cs) atomicAdd(&pooled[(size_t)g * 128 + f], a);
}

// ---------- fused fc + decoder + W3 transform ----------
__global__ __launch_bounds__(128) void fcdec_k(const float* __restrict__ pooled,
                                               const float* __restrict__ fcW,   // [128][64]
                                               const float* __restrict__ fcb,
                                               const float* __restrict__ decW,  // [64][128]
                                               const float* __restrict__ decb,
                                               const float* __restrict__ W3,    // [128][128]
                                               float* __restrict__ lat_out,
                                               float* __restrict__ zz)
{
    __shared__ float lat[64];
    __shared__ float zs[128];
    int g = blockIdx.x, c = threadIdx.x;
    if (c < 64) {
        const float* p = pooled + (size_t)g * 128;   // uniform scalar loads
        float a = fcb[c];
        #pragma unroll 8
        for (int k = 0; k < 128; k++) a = fmaf(p[k], fcW[(size_t)k * 64 + c], a);
        a = fmaxf(a, 0.f);
        lat[c] = a;
        lat_out[(size_t)g * 64 + c] = a;
    }
    __syncthreads();
    {
        float a = decb[c];
        #pragma unroll 8
        for (int k = 0; k < 64; k++) a = fmaf(lat[k], decW[(size_t)k * 128 + c], a);
        zs[c] = fmaxf(a, 0.f);
    }
    __syncthreads();
    float o = 0.f;
    #pragma unroll 8
    for (int k = 0; k < 128; k++) o = fmaf(zs[k], W3[(size_t)k * 128 + c], o);
    zz[(size_t)g * 128 + c] = o;
}

extern "C" void kernel_launch(void* const* d_in, const int* in_sizes, int n_in,
                              void* d_out, int out_size, void* d_ws, size_t ws_size,
                              hipStream_t stream)
{
    const float* x     = (const float*)d_in[0];
    const int*   ei    = (const int*)d_in[1];
    const int*   batch = (const int*)d_in[2];
    const float* W1  = (const float*)d_in[3];
    const float* b1  = (const float*)d_in[4];
    const float* W2  = (const float*)d_in[5];
    const float* b2  = (const float*)d_in[6];
    const float* fcW = (const float*)d_in[7];
    const float* fcb = (const float*)d_in[8];
    const float* decW= (const float*)d_in[9];
    const float* decb= (const float*)d_in[10];
    const float* W3  = (const float*)d_in[11];
    const float* b3  = (const float*)d_in[12];

    char* ws = (char*)d_ws;
    size_t off = 0;
    auto alloc = [&](size_t bytes) -> char* {
        char* p = ws + off;
        off = (off + bytes + 255) & ~(size_t)255;
        return p;
    };
    float* dinv     = (float*)alloc((size_t)NN * 4);
    int*   cnt      = (int*)alloc((size_t)NN * 4);
    int*   rowptr   = (int*)alloc((size_t)(NN + 1) * 4);
    int*   cursor   = (int*)alloc((size_t)NN * 4);
    int*   bsum     = (int*)alloc((size_t)NBLK * 4);
    int*   boff     = (int*)alloc(256 * 4);
    unsigned short* esrc = (unsigned short*)alloc((size_t)EE * 2);  // CSR src (ushort)
    float* pooled   = (float*)alloc((size_t)GG * 128 * 4);
    float* zz       = (float*)alloc((size_t)GG * 128 * 4);
    float* A        = (float*)alloc((size_t)NN * 128 * 4);  // prescaled ts (sliced)
    float* B        = (float*)alloc((size_t)NN * 128 * 4);  // hidden h (sliced)
    // ts3s aliases A: built only AFTER the 2nd aggs3 has consumed A
    float* ts3s     = A;

    float* recon_out = (float*)d_out;
    float* lat_out   = (float*)d_out + (size_t)NN * 128;

    hipMemsetAsync(cnt, 0, (size_t)NN * 4, stream);
    hipMemsetAsync(pooled, 0, (size_t)GG * 128 * 4, stream);
    count_k<<<(EE + 255) / 256, 256, 0, stream>>>(ei, cnt);
    bsum_k<<<NBLK, 256, 0, stream>>>(cnt, bsum);
    scanb_k<<<1, 256, 0, stream>>>(bsum, boff);
    emit_k<<<NBLK, 256, 0, stream>>>(cnt, boff, rowptr, cursor, dinv);
    fill_k<<<(EE + 255) / 256, 256, 0, stream>>>(ei, cursor, esrc);

    dim3 ggrid((NN + 255) / 256, 4);
    dim3 agrid(8, NN / 4);                   // grid.x = 8 -> slice pinned to XCD (id%8)
    // conv1: ts1 = dinv*(x @ W1) -> A(sliced) ; h1 = relu(dinv*agg(A) + b1) -> B(sliced)
    gemm128s_k<0><<<ggrid, 256, 0, stream>>>(x, W1, dinv, A, NN);
    aggs3_k<0,1><<<agrid, 256, 0, stream>>>(A, rowptr, esrc, dinv, b1, B);
    // conv2
    gemm128s_k<1><<<ggrid, 256, 0, stream>>>(B, W2, dinv, A, NN);
    aggs3_k<0,1><<<agrid, 256, 0, stream>>>(A, rowptr, esrc, dinv, b2, B);
    // pool + fused fc/dec (latent out, zz)
    pool2_k<<<dim3(GG, PCH), 128, 0, stream>>>(B, batch, pooled);
    fcdec_k<<<GG, 128, 0, stream>>>(pooled, fcW, fcb, decW, decb, W3, lat_out, zz);
    // conv3: ts3 = dinv_j * zz[batch[j]] (sliced, aliases A) ; recon row-major, no relu
    scale_k<<<(8 * NN * 16) / 256, 256, 0, stream>>>(zz, batch, dinv, ts3s);
    aggs3_k<1,0><<<agrid, 256, 0, stream>>>(ts3s, rowptr, esrc, dinv, b3, recon_out);
}